// Round 7
// baseline (348.227 us; speedup 1.0000x reference)
//
#include <hip/hip_runtime.h>
#include <hip/hip_bf16.h>

#define IN_F   4096
#define OUT_F  4096
#define PACKED (IN_F / 8)      // 512
#define M_DIM  8192            // 4 * 2048
#define N_DIM  4096
#define K_DIM  4096

#define BM 128
#define BN 128
#define BK 64
#define NT (K_DIM / BK)        // 64 K-tiles

typedef __bf16 bf16x8 __attribute__((ext_vector_type(8)));
typedef float  f32x4  __attribute__((ext_vector_type(4)));

#define BAR() asm volatile("s_barrier" ::: "memory")
#define VMCNT(n) asm volatile("s_waitcnt vmcnt(" #n ")" ::: "memory")

// ---------------------------------------------------------------------------
// Fragment-ordered DRAM layout for both GEMM operands (produced by prepasses):
//   [128-row-half][kTile(64)][subtile st(16)][1024 B]
//   subtile st: rows (st>>1)*16..+15 (within the half), cols (st&1)*32..+31
//   within subtile, chunk l (=byte/16): row16 = l&15, k8 = (l>>4)*8
// A wave staging a subtile reads a CONTIGUOUS 1 KB; ds_read_b128 fragment
// reads are lane-linear (0 bank conflicts). A 128x128 GEMM tile uses exactly
// one 128-row half per operand per K-tile (16 KB contiguous).
// ---------------------------------------------------------------------------

// Pre-pass 1: dequantize int4 -> bf16 fragment-ordered W.
__global__ __launch_bounds__(256) void dequant_kernel(
    const int* __restrict__ qw, const float* __restrict__ qs,
    const int* __restrict__ qz, __bf16* __restrict__ W)
{
    int ch = blockIdx.x * blockDim.x + threadIdx.x;
    if (ch >= OUT_F * PACKED) return;
    int l     = ch & 63;
    int st    = (ch >> 6) & 15;
    int kTile = (ch >> 10) & 63;
    int nHalf = ch >> 16;
    int o  = nHalf * 128 + ((st >> 1) << 4) + (l & 15);
    int k0 = kTile * 64 + ((st & 1) << 5) + ((l >> 4) << 3);
    int g  = k0 >> 7;
    unsigned int q = (unsigned int)qw[o * PACKED + (k0 >> 3)];
    float scale = qs[g * OUT_F + o];
    float zero  = (float)qz[g * OUT_F + o];
    bf16x8 v;
#pragma unroll
    for (int i = 0; i < 8; ++i) {
        float wi = (float)((q >> (4 * i)) & 15u);
        v[i] = (__bf16)((wi - zero) * scale);
    }
    *reinterpret_cast<bf16x8*>(&W[(size_t)ch * 8]) = v;
}

// Pre-pass 2: x f32 -> bf16 fragment-ordered xb.
__global__ __launch_bounds__(256) void cvt_kernel(
    const float* __restrict__ x, __bf16* __restrict__ xb, int nch)
{
    int ch = blockIdx.x * blockDim.x + threadIdx.x;
    if (ch >= nch) return;
    int l     = ch & 63;
    int st    = (ch >> 6) & 15;
    int kTile = (ch >> 10) & 63;
    int mHalf = ch >> 16;
    int m  = mHalf * 128 + ((st >> 1) << 4) + (l & 15);
    int k0 = kTile * 64 + ((st & 1) << 5) + ((l >> 4) << 3);
    const float4* xv = reinterpret_cast<const float4*>(x + (size_t)m * K_DIM + k0);
    float4 a = xv[0];
    float4 b = xv[1];
    bf16x8 v;
    v[0] = (__bf16)a.x; v[1] = (__bf16)a.y; v[2] = (__bf16)a.z; v[3] = (__bf16)a.w;
    v[4] = (__bf16)b.x; v[5] = (__bf16)b.y; v[6] = (__bf16)b.z; v[7] = (__bf16)b.w;
    reinterpret_cast<bf16x8*>(xb)[ch] = v;
}

// ---------------------------------------------------------------------------
// GEMM: 128x128 tile, BK=64, 4 waves (2Mx2N, 64x64/wave), 64 KiB LDS dbuf ->
// TWO blocks co-resident per CU (independent barrier domains). Block A's
// read/barrier phases overlap block B's MFMA on the other pipe.
// 2 phases/K-tile:
//   p0: read A(8)+B01(4); stage B(t+1)->other buf; Q01 = A*B01
//   p1: read B23(4);      stage A(t+2)->own buf;   Q23 = A*B23; VMCNT(4)
// ---------------------------------------------------------------------------
__global__ __launch_bounds__(256, 2) void gemm_kernel(
    const __bf16* __restrict__ A, const __bf16* __restrict__ B,
    float* __restrict__ C)
{
    extern __shared__ __bf16 lds[];   // [A0|B0|A1|B1] x 8192 elems = 64 KiB

    const int tid  = threadIdx.x;
    const int lane = tid & 63;
    const int wave = tid >> 6;        // 0..3
    const int wm   = wave >> 1;       // 0..1
    const int wn   = wave & 1;        // 0..1

    // bijective XCD swizzle: 2048 blocks = 8 XCDs x 256
    const int bid = blockIdx.x;
    const int swz = (bid & 7) * 256 + (bid >> 3);
    const int nBase = (swz & 31) * BN;
    const int mBase = (swz >> 5) * BM;
    const int mHalf = mBase >> 7;
    const int nHalf = nBase >> 7;

    const int lr = lane & 15;

    // stage one 128x64 operand K-tile (16 contiguous-1KB subtiles): 4 loads/thread
    auto stage = [&](const __bf16* __restrict__ srcFrag, __bf16* dst,
                     int halfG, int kTile) {
        const __bf16* src = srcFrag + ((size_t)(halfG * 64 + kTile) << 13);
#pragma unroll
        for (int i = 0; i < 4; ++i) {
            const int st = i * 4 + wave;          // wave-uniform
            __builtin_amdgcn_global_load_lds(
                (const __attribute__((address_space(1))) void*)(src + st * 512 + lane * 8),
                (__attribute__((address_space(3))) void*)(dst + st * 512 + lane * 8),
                16, 0, 0);
        }
    };

    f32x4 acc[4][4];
#pragma unroll
    for (int i = 0; i < 4; ++i)
#pragma unroll
        for (int j = 0; j < 4; ++j)
            acc[i][j] = 0.0f;

    bf16x8 Af[4][2];
    bf16x8 Bf[2][2];

#define LDA(buf, mi, kb) (*(const bf16x8*)((buf) + (((wm * 4 + (mi)) * 2 + (kb)) * 512 + lane * 8)))
#define LDB(buf, nj, kb) (*(const bf16x8*)((buf) + (((wn * 4 + (nj)) * 2 + (kb)) * 512 + lane * 8)))

    // Prologue (FIFO order): A(0), B(0), A(1)
    stage(A, lds,         mHalf, 0);
    stage(B, lds + 8192,  nHalf, 0);
    stage(A, lds + 16384, mHalf, 1);
    VMCNT(4);                          // A(0),B(0) retired; A(1) in flight
    BAR();

    for (int t = 0; t < NT; ++t) {
        __bf16* base = lds + (size_t)(t & 1) * 16384;
        const __bf16* cA = base;
        const __bf16* cB = base + 8192;
        __bf16* nB = lds + (size_t)((t + 1) & 1) * 16384 + 8192;

        // ---- p0: read A (8) + B01 (4); stage B(t+1); Q01
#pragma unroll
        for (int mi = 0; mi < 4; ++mi) { Af[mi][0] = LDA(cA, mi, 0); Af[mi][1] = LDA(cA, mi, 1); }
#pragma unroll
        for (int nj = 0; nj < 2; ++nj) { Bf[nj][0] = LDB(cB, nj, 0); Bf[nj][1] = LDB(cB, nj, 1); }
        __builtin_amdgcn_sched_barrier(0);
        if (t < NT - 1) stage(B, nB, nHalf, t + 1);
        BAR();
        __builtin_amdgcn_s_setprio(1);
#pragma unroll
        for (int kb = 0; kb < 2; ++kb)
#pragma unroll
            for (int mi = 0; mi < 4; ++mi)
#pragma unroll
                for (int nj = 0; nj < 2; ++nj)
                    acc[mi][nj] = __builtin_amdgcn_mfma_f32_16x16x32_bf16(Af[mi][kb], Bf[nj][kb], acc[mi][nj], 0, 0, 0);
        __builtin_amdgcn_s_setprio(0);
        BAR();

        // ---- p1: read B23 (4, overwrite Bf); stage A(t+2); Q23; counted vmcnt
#pragma unroll
        for (int nj = 0; nj < 2; ++nj) { Bf[nj][0] = LDB(cB, nj + 2, 0); Bf[nj][1] = LDB(cB, nj + 2, 1); }
        __builtin_amdgcn_sched_barrier(0);
        if (t < NT - 2) stage(A, base, mHalf, t + 2);
        BAR();
        __builtin_amdgcn_s_setprio(1);
#pragma unroll
        for (int kb = 0; kb < 2; ++kb)
#pragma unroll
            for (int mi = 0; mi < 4; ++mi)
#pragma unroll
                for (int nj = 0; nj < 2; ++nj)
                    acc[mi][nj + 2] = __builtin_amdgcn_mfma_f32_16x16x32_bf16(Af[mi][kb], Bf[nj][kb], acc[mi][nj + 2], 0, 0, 0);
        __builtin_amdgcn_s_setprio(0);
        if (t < NT - 2)       VMCNT(4);   // retires A(t+1),B(t+1); A(t+2) in flight
        else if (t == NT - 2) VMCNT(0);   // final drain
        BAR();
    }

    // Epilogue: C/D layout col=lane&15, row=(lane>>4)*4+reg
#pragma unroll
    for (int mi = 0; mi < 4; ++mi)
#pragma unroll
        for (int nj = 0; nj < 4; ++nj) {
            const int col = nBase + wn * 64 + nj * 16 + lr;
#pragma unroll
            for (int r = 0; r < 4; ++r) {
                const int row = mBase + wm * 64 + mi * 16 + (lane >> 4) * 4 + r;
                C[(size_t)row * N_DIM + col] = (float)(__bf16)acc[mi][nj][r];
            }
        }
#undef LDA
#undef LDB
}

extern "C" void kernel_launch(void* const* d_in, const int* in_sizes, int n_in,
                              void* d_out, int out_size, void* d_ws, size_t ws_size,
                              hipStream_t stream)
{
    const float* x       = (const float*)d_in[0];
    const int*   qweight = (const int*)d_in[1];
    const float* qscale  = (const float*)d_in[2];
    const int*   qzeros  = (const int*)d_in[3];
    float*       out     = (float*)d_out;

    __bf16* W  = (__bf16*)d_ws;
    __bf16* xb = (__bf16*)((char*)d_ws + (size_t)N_DIM * K_DIM * sizeof(__bf16));

    {
        int total = OUT_F * PACKED;
        dequant_kernel<<<(total + 255) / 256, 256, 0, stream>>>(qweight, qscale, qzeros, W);
    }
    {
        int nch = (M_DIM * K_DIM) / 8;
        cvt_kernel<<<(nch + 255) / 256, 256, 0, stream>>>(x, xb, nch);
    }
    {
        (void)hipFuncSetAttribute((const void*)gemm_kernel,
                                  hipFuncAttributeMaxDynamicSharedMemorySize, 65536);
        dim3 grid((M_DIM / BM) * (N_DIM / BN));   // 64 x 32 = 2048 blocks
        gemm_kernel<<<grid, 256, 65536, stream>>>(xb, W, out);
    }
}

// Round 8
// 292.570 us; speedup vs baseline: 1.1902x; 1.1902x over previous
//
#include <hip/hip_runtime.h>
#include <hip/hip_bf16.h>

#define IN_F   4096
#define OUT_F  4096
#define PACKED (IN_F / 8)      // 512
#define M_DIM  8192            // 4 * 2048
#define N_DIM  4096
#define K_DIM  4096

#define BM 256
#define BN 256
#define BK 32
#define NT (K_DIM / BK)        // 128 K-steps

typedef __bf16 bf16x8 __attribute__((ext_vector_type(8)));
typedef float  f32x4  __attribute__((ext_vector_type(4)));

#define BAR() asm volatile("s_barrier" ::: "memory")
#define VMCNT(n) asm volatile("s_waitcnt vmcnt(" #n ")" ::: "memory")
#define AS1 __attribute__((address_space(1)))
#define AS3 __attribute__((address_space(3)))

// ---------------------------------------------------------------------------
// Fragment-ordered DRAM layout for both GEMM operands (produced by prepasses):
//   [128-row-half][kTile64(64)][subtile st(16)][1024 B]
//   subtile st: rows (st>>1)*16..+15 (within the half), k-cols (st&1)*32..+31
//   within subtile, chunk l (=byte/16): row16 = l&15, k8 = (l>>4)*8
// A wave staging a subtile reads a CONTIGUOUS 1 KB; ds_read_b128 fragment
// reads are lane-linear (0 bank conflicts). A BK=32 K-step uses the 8
// subtiles of one 64-K-tile with matching k-parity (st = rb*2 + kpar).
// ---------------------------------------------------------------------------

// Pre-pass 1: dequantize int4 -> bf16 fragment-ordered W.
__global__ __launch_bounds__(256) void dequant_kernel(
    const int* __restrict__ qw, const float* __restrict__ qs,
    const int* __restrict__ qz, __bf16* __restrict__ W)
{
    int ch = blockIdx.x * blockDim.x + threadIdx.x;
    if (ch >= OUT_F * PACKED) return;
    int l     = ch & 63;
    int st    = (ch >> 6) & 15;
    int kTile = (ch >> 10) & 63;
    int nHalf = ch >> 16;
    int o  = nHalf * 128 + ((st >> 1) << 4) + (l & 15);
    int k0 = kTile * 64 + ((st & 1) << 5) + ((l >> 4) << 3);
    int g  = k0 >> 7;
    unsigned int q = (unsigned int)qw[o * PACKED + (k0 >> 3)];
    float scale = qs[g * OUT_F + o];
    float zero  = (float)qz[g * OUT_F + o];
    bf16x8 v;
#pragma unroll
    for (int i = 0; i < 8; ++i) {
        float wi = (float)((q >> (4 * i)) & 15u);
        v[i] = (__bf16)((wi - zero) * scale);
    }
    *reinterpret_cast<bf16x8*>(&W[(size_t)ch * 8]) = v;
}

// Pre-pass 2: x f32 -> bf16 fragment-ordered xb.
__global__ __launch_bounds__(256) void cvt_kernel(
    const float* __restrict__ x, __bf16* __restrict__ xb, int nch)
{
    int ch = blockIdx.x * blockDim.x + threadIdx.x;
    if (ch >= nch) return;
    int l     = ch & 63;
    int st    = (ch >> 6) & 15;
    int kTile = (ch >> 10) & 63;
    int mHalf = ch >> 16;
    int m  = mHalf * 128 + ((st >> 1) << 4) + (l & 15);
    int k0 = kTile * 64 + ((st & 1) << 5) + ((l >> 4) << 3);
    const float4* xv = reinterpret_cast<const float4*>(x + (size_t)m * K_DIM + k0);
    float4 a = xv[0];
    float4 b = xv[1];
    bf16x8 v;
    v[0] = (__bf16)a.x; v[1] = (__bf16)a.y; v[2] = (__bf16)a.z; v[3] = (__bf16)a.w;
    v[4] = (__bf16)b.x; v[5] = (__bf16)b.y; v[6] = (__bf16)b.z; v[7] = (__bf16)b.w;
    reinterpret_cast<bf16x8*>(xb)[ch] = v;
}

// ---------------------------------------------------------------------------
// GEMM: 256x256 tile, BK=32, 8 waves (2Mx4N, 128x64 out per wave).
// LOOSE schedule: ONE barrier per K-step, tri-buffered LDS (3 x 32 KiB),
// staging 2 K-steps ahead, counted VMCNT(4) (never drains mid-loop).
// Within a window waves drift -> one wave's ds_reads overlap another's MFMA.
// Window t:
//   stage(t+2) -> buf[(t+2)%3]   (WAR-safe: that buf's reads ended pre BAR_t)
//   12 ds_read (Af[8], Bf[4]) from buf[t%3]
//   32 MFMA (compiler fine-lgkm interleaves with read completions)
//   VMCNT(4)  [retires stage(t+1): published for next window]
//   BAR
// ---------------------------------------------------------------------------
__global__ __launch_bounds__(512, 2) void gemm_kernel(
    const __bf16* __restrict__ A, const __bf16* __restrict__ B,
    float* __restrict__ C)
{
    extern __shared__ __bf16 lds[];   // 3 bufs x (A 8192 + B 8192) = 96 KiB

    const int tid  = threadIdx.x;
    const int lane = tid & 63;
    const int wave = tid >> 6;        // 0..7
    const int wm   = wave >> 2;       // 0..1
    const int wn   = wave & 3;        // 0..3

    // bijective XCD swizzle: 512 blocks = 8 XCDs x 64
    const int bid = blockIdx.x;
    const int swz = (bid & 7) * 64 + (bid >> 3);
    const int nBase = (swz & 15) * BN;
    const int mBase = (swz >> 4) * BM;
    const int mHalf = mBase >> 7;
    const int nHalf = nBase >> 7;

    const int lr = lane & 15;

    // stage one 256x32 A-step + 256x32 B-step (32 subtiles, 4 loads/wave)
    auto stage_tile = [&](int bufIdx, int t32) {
        __bf16* dst = lds + bufIdx * 16384;
        const int kT = t32 >> 1;
        const int kp = t32 & 1;
#pragma unroll
        for (int i = 0; i < 4; ++i) {
            const int s    = i * 8 + wave;    // 0..31, wave-uniform
            const int isB  = (i >> 1);        // i0,i1 -> A; i2,i3 -> B
            const int half = (i & 1);
            const int srcHalf = (isB ? nHalf : mHalf) + half;
            const __bf16* src = (isB ? B : A)
                + ((size_t)(srcHalf * 64 + kT) << 13)
                + (wave * 2 + kp) * 512;
            __builtin_amdgcn_global_load_lds(
                (const AS1 void*)(src + lane * 8),
                (AS3 void*)(dst + s * 512 + lane * 8), 16, 0, 0);
        }
    };

    f32x4 acc[8][4];
#pragma unroll
    for (int i = 0; i < 8; ++i)
#pragma unroll
        for (int j = 0; j < 4; ++j)
            acc[i][j] = 0.0f;

#define LDA(buf, mi) (*(const bf16x8*)((buf) + ((wm * 8 + (mi)) * 512 + lane * 8)))
#define LDB(buf, nj) (*(const bf16x8*)((buf) + 8192 + ((wn * 4 + (nj)) * 512 + lane * 8)))

    // Prologue: stage K-steps 0 and 1; retire 0, keep 1 in flight.
    stage_tile(0, 0);
    stage_tile(1, 1);
    VMCNT(4);
    BAR();

    for (int t = 0; t < NT; ++t) {
        const __bf16* cur = lds + (t % 3) * 16384;

        if (t + 2 < NT) stage_tile((t + 2) % 3, t + 2);
        __builtin_amdgcn_sched_barrier(0);

        bf16x8 Af[8], Bf[4];
        Af[0] = LDA(cur, 0);
#pragma unroll
        for (int nj = 0; nj < 4; ++nj) Bf[nj] = LDB(cur, nj);
#pragma unroll
        for (int mi = 1; mi < 8; ++mi) Af[mi] = LDA(cur, mi);

#pragma unroll
        for (int mi = 0; mi < 8; ++mi)
#pragma unroll
            for (int nj = 0; nj < 4; ++nj)
                acc[mi][nj] = __builtin_amdgcn_mfma_f32_16x16x32_bf16(
                    Af[mi], Bf[nj], acc[mi][nj], 0, 0, 0);

        if (t < NT - 2)       VMCNT(4);   // retires stage(t+1); stage(t+2) stays in flight
        else if (t == NT - 2) VMCNT(0);   // final drain for last K-step
        BAR();
    }

    // Epilogue: C/D layout col=lane&15, row=(lane>>4)*4+reg
#pragma unroll
    for (int mi = 0; mi < 8; ++mi)
#pragma unroll
        for (int nj = 0; nj < 4; ++nj) {
            const int col = nBase + wn * 64 + nj * 16 + lr;
#pragma unroll
            for (int r = 0; r < 4; ++r) {
                const int row = mBase + wm * 128 + mi * 16 + (lane >> 4) * 4 + r;
                C[(size_t)row * N_DIM + col] = (float)(__bf16)acc[mi][nj][r];
            }
        }
#undef LDA
#undef LDB
}

extern "C" void kernel_launch(void* const* d_in, const int* in_sizes, int n_in,
                              void* d_out, int out_size, void* d_ws, size_t ws_size,
                              hipStream_t stream)
{
    const float* x       = (const float*)d_in[0];
    const int*   qweight = (const int*)d_in[1];
    const float* qscale  = (const float*)d_in[2];
    const int*   qzeros  = (const int*)d_in[3];
    float*       out     = (float*)d_out;

    __bf16* W  = (__bf16*)d_ws;
    __bf16* xb = (__bf16*)((char*)d_ws + (size_t)N_DIM * K_DIM * sizeof(__bf16));

    {
        int total = OUT_F * PACKED;
        dequant_kernel<<<(total + 255) / 256, 256, 0, stream>>>(qweight, qscale, qzeros, W);
    }
    {
        int nch = (M_DIM * K_DIM) / 8;
        cvt_kernel<<<(nch + 255) / 256, 256, 0, stream>>>(x, xb, nch);
    }
    {
        (void)hipFuncSetAttribute((const void*)gemm_kernel,
                                  hipFuncAttributeMaxDynamicSharedMemorySize, 98304);
        dim3 grid((M_DIM / BM) * (N_DIM / BN));   // 512 blocks
        gemm_kernel<<<grid, 512, 98304, stream>>>(xb, W, out);
    }
}

// Round 9
// 283.813 us; speedup vs baseline: 1.2270x; 1.0309x over previous
//
#include <hip/hip_runtime.h>
#include <hip/hip_bf16.h>

#define IN_F   4096
#define OUT_F  4096
#define PACKED (IN_F / 8)      // 512
#define M_DIM  8192            // 4 * 2048
#define N_DIM  4096
#define K_DIM  4096

#define BM 256
#define BN 256
#define BK 64
#define NT (K_DIM / BK)        // 64 K-tiles

typedef __bf16 bf16x8 __attribute__((ext_vector_type(8)));
typedef float  f32x4  __attribute__((ext_vector_type(4)));

#define BAR() asm volatile("s_barrier" ::: "memory")
#define VMCNT(n) asm volatile("s_waitcnt vmcnt(" #n ")" ::: "memory")
#define AS1 __attribute__((address_space(1)))
#define AS3 __attribute__((address_space(3)))

// ---------------------------------------------------------------------------
// Fragment-ordered DRAM layout for both GEMM operands (produced by prepasses):
//   [128-row-half][kTile64(64)][subtile st(16)][1024 B]
//   subtile st: rows (st>>1)*16..+15 (within the half), k-cols (st&1)*32..+31
//   within subtile, chunk l (=byte/16): row16 = l&15, k8 = (l>>4)*8
// A wave staging/reading a subtile touches a CONTIGUOUS 1 KB.
// ---------------------------------------------------------------------------

// Pre-pass 1: dequantize int4 -> bf16 fragment-ordered W.
__global__ __launch_bounds__(256) void dequant_kernel(
    const int* __restrict__ qw, const float* __restrict__ qs,
    const int* __restrict__ qz, __bf16* __restrict__ W)
{
    int ch = blockIdx.x * blockDim.x + threadIdx.x;
    if (ch >= OUT_F * PACKED) return;
    int l     = ch & 63;
    int st    = (ch >> 6) & 15;
    int kTile = (ch >> 10) & 63;
    int nHalf = ch >> 16;
    int o  = nHalf * 128 + ((st >> 1) << 4) + (l & 15);
    int k0 = kTile * 64 + ((st & 1) << 5) + ((l >> 4) << 3);
    int g  = k0 >> 7;
    unsigned int q = (unsigned int)qw[o * PACKED + (k0 >> 3)];
    float scale = qs[g * OUT_F + o];
    float zero  = (float)qz[g * OUT_F + o];
    bf16x8 v;
#pragma unroll
    for (int i = 0; i < 8; ++i) {
        float wi = (float)((q >> (4 * i)) & 15u);
        v[i] = (__bf16)((wi - zero) * scale);
    }
    *reinterpret_cast<bf16x8*>(&W[(size_t)ch * 8]) = v;
}

// Pre-pass 2: x f32 -> bf16 fragment-ordered xb.
__global__ __launch_bounds__(256) void cvt_kernel(
    const float* __restrict__ x, __bf16* __restrict__ xb, int nch)
{
    int ch = blockIdx.x * blockDim.x + threadIdx.x;
    if (ch >= nch) return;
    int l     = ch & 63;
    int st    = (ch >> 6) & 15;
    int kTile = (ch >> 10) & 63;
    int mHalf = ch >> 16;
    int m  = mHalf * 128 + ((st >> 1) << 4) + (l & 15);
    int k0 = kTile * 64 + ((st & 1) << 5) + ((l >> 4) << 3);
    const float4* xv = reinterpret_cast<const float4*>(x + (size_t)m * K_DIM + k0);
    float4 a = xv[0];
    float4 b = xv[1];
    bf16x8 v;
    v[0] = (__bf16)a.x; v[1] = (__bf16)a.y; v[2] = (__bf16)a.z; v[3] = (__bf16)a.w;
    v[4] = (__bf16)b.x; v[5] = (__bf16)b.y; v[6] = (__bf16)b.z; v[7] = (__bf16)b.w;
    reinterpret_cast<bf16x8*>(xb)[ch] = v;
}

// ---------------------------------------------------------------------------
// GEMM: 256x256 tile, BK=64, 8 waves (2Mx4N). A staged via tri-buffered LDS
// (96 KiB, 2 tiles ahead); B fragments DIRECT global->VGPR (contiguous 1 KB
// per wave-read, L2-served, refilled after last use, one phase of latency
// slack). 3 phases/K-tile:
//   pA: ds_read A03(t)[8];                  BAR; Q0 = A03*Bc01;            BAR
//   pB: stage Ah0(t+2)[2];                  BAR; Q1 = A03*Bc23;            BAR
//   pC: ds_read A47(t)[8]; stage Ah1(t+2);  BAR; Q2 = A47*Bc01;
//       load Bc01(t+1); Q3 = A47*Bc23; load Bc23(t+1); VMCNT(12);          BAR
// VMCNT(12) retires A-stage(t+1) (published by BAR) and keeps
// {A-stage(t+2)=4, B(t+1)=8} in flight.
// ---------------------------------------------------------------------------
__global__ __launch_bounds__(512, 2) void gemm_kernel(
    const __bf16* __restrict__ A, const __bf16* __restrict__ B,
    float* __restrict__ C)
{
    extern __shared__ __bf16 lds[];   // 3 bufs x 16384 bf16 (A only) = 96 KiB

    const int tid  = threadIdx.x;
    const int lane = tid & 63;
    const int wave = tid >> 6;        // 0..7
    const int wm   = wave >> 2;       // 0..1
    const int wn   = wave & 3;        // 0..3
    const int wm8  = wm * 8;
    const int wn4  = wn * 4;
    const int lane8 = lane * 8;

    // bijective XCD swizzle: 512 blocks = 8 XCDs x 64
    const int bid = blockIdx.x;
    const int swz = (bid & 7) * 64 + (bid >> 3);
    const int nBase = (swz & 15) * BN;
    const int mBase = (swz >> 4) * BM;
    const int mHalf = mBase >> 7;
    const int nHalf = nBase >> 7;

    const int lr = lane & 15;

    // stage one 128x64 A half (16 subtiles): 2 contiguous-1KB loads/thread
    auto stageA = [&](int t, int h) {
        __bf16* dst = lds + (t % 3) * 16384 + h * 8192;
        const __bf16* src = A + ((size_t)((mHalf + h) * 64 + t) << 13);
#pragma unroll
        for (int i = 0; i < 2; ++i) {
            const int st = i * 8 + wave;          // wave-uniform
            __builtin_amdgcn_global_load_lds(
                (const AS1 void*)(src + st * 512 + lane8),
                (AS3 void*)(dst + st * 512 + lane8), 16, 0, 0);
        }
    };

    f32x4 acc[8][4];
#pragma unroll
    for (int i = 0; i < 8; ++i)
#pragma unroll
        for (int j = 0; j < 4; ++j)
            acc[i][j] = 0.0f;

    bf16x8 Af[4][2];
    bf16x8 Bc[4][2];

#define LDA_(cA, mi, kb) (*(const bf16x8*)((cA) + (((wm8 + (mi)) * 2 + (kb)) << 9) + lane8))
// direct global B-fragment load: contiguous 1 KB per wave
#define LOADB2(njBase, tt) do { \
    _Pragma("unroll") \
    for (int _nj = 0; _nj < 2; ++_nj) { \
        const int _rb = wn4 + (njBase) + _nj; \
        _Pragma("unroll") \
        for (int _kb = 0; _kb < 2; ++_kb) { \
            const __bf16* _p = B + ((size_t)((nHalf + (_rb >> 3)) * 64 + (tt)) << 13) \
                                 + (((_rb & 7) * 2 + _kb) << 9) + lane8; \
            Bc[(njBase) + _nj][_kb] = *reinterpret_cast<const bf16x8*>(_p); \
        } \
    } \
} while (0)

    // Prologue (FIFO order): B(0)[8], stage A(0)[4], stage A(1)[4]
    LOADB2(0, 0);
    LOADB2(2, 0);
    stageA(0, 0); stageA(0, 1);
    stageA(1, 0); stageA(1, 1);
    VMCNT(4);                          // retires B(0)+A(0); A(1) in flight
    BAR();

    for (int t = 0; t < NT; ++t) {
        const __bf16* cA = lds + (t % 3) * 16384;

        // ---- pA: read A03(t); BAR; Q0 = A03*Bc01
#pragma unroll
        for (int mi = 0; mi < 4; ++mi) { Af[mi][0] = LDA_(cA, mi, 0); Af[mi][1] = LDA_(cA, mi, 1); }
        __builtin_amdgcn_sched_barrier(0);
        BAR();
        __builtin_amdgcn_s_setprio(1);
#pragma unroll
        for (int kb = 0; kb < 2; ++kb)
#pragma unroll
            for (int mi = 0; mi < 4; ++mi)
#pragma unroll
                for (int nj = 0; nj < 2; ++nj)
                    acc[mi][nj] = __builtin_amdgcn_mfma_f32_16x16x32_bf16(Af[mi][kb], Bc[nj][kb], acc[mi][nj], 0, 0, 0);
        __builtin_amdgcn_s_setprio(0);
        BAR();

        // ---- pB: stage Ah0(t+2); BAR; Q1 = A03*Bc23
        if (t < NT - 2) stageA(t + 2, 0);
        __builtin_amdgcn_sched_barrier(0);
        BAR();
        __builtin_amdgcn_s_setprio(1);
#pragma unroll
        for (int kb = 0; kb < 2; ++kb)
#pragma unroll
            for (int mi = 0; mi < 4; ++mi)
#pragma unroll
                for (int nj = 0; nj < 2; ++nj)
                    acc[mi][nj + 2] = __builtin_amdgcn_mfma_f32_16x16x32_bf16(Af[mi][kb], Bc[nj + 2][kb], acc[mi][nj + 2], 0, 0, 0);
        __builtin_amdgcn_s_setprio(0);
        BAR();

        // ---- pC: read A47(t); stage Ah1(t+2); BAR; Q2; refill Bc01(t+1);
        //          Q3; refill Bc23(t+1); counted vmcnt; BAR
#pragma unroll
        for (int mi = 0; mi < 4; ++mi) { Af[mi][0] = LDA_(cA, mi + 4, 0); Af[mi][1] = LDA_(cA, mi + 4, 1); }
        if (t < NT - 2) stageA(t + 2, 1);
        __builtin_amdgcn_sched_barrier(0);
        BAR();
        __builtin_amdgcn_s_setprio(1);
#pragma unroll
        for (int kb = 0; kb < 2; ++kb)
#pragma unroll
            for (int mi = 0; mi < 4; ++mi)
#pragma unroll
                for (int nj = 0; nj < 2; ++nj)
                    acc[mi + 4][nj] = __builtin_amdgcn_mfma_f32_16x16x32_bf16(Af[mi][kb], Bc[nj][kb], acc[mi + 4][nj], 0, 0, 0);
        if (t < NT - 1) LOADB2(0, t + 1);    // Bc01 dead after Q2 -> refill
#pragma unroll
        for (int kb = 0; kb < 2; ++kb)
#pragma unroll
            for (int mi = 0; mi < 4; ++mi)
#pragma unroll
                for (int nj = 0; nj < 2; ++nj)
                    acc[mi + 4][nj + 2] = __builtin_amdgcn_mfma_f32_16x16x32_bf16(Af[mi][kb], Bc[nj + 2][kb], acc[mi + 4][nj + 2], 0, 0, 0);
        if (t < NT - 1) LOADB2(2, t + 1);    // Bc23 dead after Q3 -> refill
        __builtin_amdgcn_s_setprio(0);
        if (t < NT - 2)       VMCNT(12);  // retire A-stage(t+1); keep A(t+2)+B(t+1)
        else if (t == NT - 2) VMCNT(8);   // retire A-stage(NT-1); keep B(NT-1)
        BAR();
    }

    // Epilogue: C/D layout col=lane&15, row=(lane>>4)*4+reg
#pragma unroll
    for (int mi = 0; mi < 8; ++mi)
#pragma unroll
        for (int nj = 0; nj < 4; ++nj) {
            const int col = nBase + wn * 64 + nj * 16 + lr;
#pragma unroll
            for (int r = 0; r < 4; ++r) {
                const int row = mBase + wm * 128 + mi * 16 + (lane >> 4) * 4 + r;
                C[(size_t)row * N_DIM + col] = (float)(__bf16)acc[mi][nj][r];
            }
        }
#undef LDA_
#undef LOADB2
}

extern "C" void kernel_launch(void* const* d_in, const int* in_sizes, int n_in,
                              void* d_out, int out_size, void* d_ws, size_t ws_size,
                              hipStream_t stream)
{
    const float* x       = (const float*)d_in[0];
    const int*   qweight = (const int*)d_in[1];
    const float* qscale  = (const float*)d_in[2];
    const int*   qzeros  = (const int*)d_in[3];
    float*       out     = (float*)d_out;

    __bf16* W  = (__bf16*)d_ws;
    __bf16* xb = (__bf16*)((char*)d_ws + (size_t)N_DIM * K_DIM * sizeof(__bf16));

    {
        int total = OUT_F * PACKED;
        dequant_kernel<<<(total + 255) / 256, 256, 0, stream>>>(qweight, qscale, qzeros, W);
    }
    {
        int nch = (M_DIM * K_DIM) / 8;
        cvt_kernel<<<(nch + 255) / 256, 256, 0, stream>>>(x, xb, nch);
    }
    {
        (void)hipFuncSetAttribute((const void*)gemm_kernel,
                                  hipFuncAttributeMaxDynamicSharedMemorySize, 98304);
        dim3 grid((M_DIM / BM) * (N_DIM / BN));   // 512 blocks
        gemm_kernel<<<grid, 512, 98304, stream>>>(xb, W, out);
    }
}